// Round 7
// baseline (104.076 us; speedup 1.0000x reference)
//
#include <hip/hip_runtime.h>

// Problem constants
#define NMOLS   256
#define NATOMS  32
#define REPD    256
#define NPCAS   128
#define NSTACKS 32
#define NFEAT   4096
#define NELEM   4

// ws layout (bytes)
#define LIST_OFF 0          // int list[8192]
#define META_OFF 32768      // int meta[16]
#define SUB_OFF  40960      // float sub[8192*128]

#define SCALE_C 0.029462782549439476f   // sqrt(128)/(3*128)
#define FEATN_C 0.022097086912079608f   // sqrt(2/4096)

__device__ __forceinline__ int elem_of(int z) {
  return (z == 1) ? 0 : (z == 6) ? 1 : (z == 7) ? 2 : (z == 8) ? 3 : -1;
}

// ---------------- K0: bucket atoms by element (deterministic), zero out ----------------
__global__ __launch_bounds__(256) void k0_bucket(const int* __restrict__ Z,
                                                 int* __restrict__ list,
                                                 int* __restrict__ meta,
                                                 float* __restrict__ out) {
  __shared__ int4 cntS[256];
  const int t = threadIdx.x;
  out[t] = 0.0f;
  int c0 = 0, c1 = 0, c2 = 0, c3 = 0;
  #pragma unroll
  for (int k = 0; k < 32; ++k) {
    const int z = Z[k * 256 + t];
    c0 += (z == 1); c1 += (z == 6); c2 += (z == 7); c3 += (z == 8);
  }
  int4 v = make_int4(c0, c1, c2, c3);
  cntS[t] = v;
  __syncthreads();
  for (int step = 1; step < 256; step <<= 1) {
    int4 add = make_int4(0, 0, 0, 0);
    if (t >= step) add = cntS[t - step];
    __syncthreads();
    v.x += add.x; v.y += add.y; v.z += add.z; v.w += add.w;
    cntS[t] = v;
    __syncthreads();
  }
  const int4 tot = cntS[255];
  int o0 = v.x - c0;
  int o1 = tot.x + v.y - c1;
  int o2 = tot.x + tot.y + v.z - c2;
  int o3 = tot.x + tot.y + tot.z + v.w - c3;
  #pragma unroll
  for (int k = 0; k < 32; ++k) {
    const int a = k * 256 + t;
    const int z = Z[a];
    if      (z == 1) list[o0++] = a;
    else if (z == 6) list[o1++] = a;
    else if (z == 7) list[o2++] = a;
    else if (z == 8) list[o3++] = a;
  }
  if (t == 0) {
    meta[0] = tot.x; meta[1] = tot.y; meta[2] = tot.z; meta[3] = tot.w;
    meta[4] = 0;
    meta[5] = tot.x;
    meta[6] = tot.x + tot.y;
    meta[7] = tot.x + tot.y + tot.z;
    meta[8] = tot.x + tot.y + tot.z + tot.w;
  }
}

// ---------------- K1: 8-atom tiles, 1 atom x 4 p per thread, full-K LDS stage ----------------
// grid (1024, 4). repS 8KB -> many blocks/CU. Per wave: 2 distinct LDS addrs (free bcast).
__global__ __launch_bounds__(256) void k1_matvec(const float* __restrict__ rep,
                                                 const float* __restrict__ reductors,
                                                 const int* __restrict__ list,
                                                 const int* __restrict__ meta,
                                                 float* __restrict__ sub) {
  const int e = blockIdx.y;
  const int cnt = meta[e];
  const int off = meta[4 + e];
  const int start = blockIdx.x * 8;
  if (start >= cnt) return;
  const int n = min(8, cnt - start);
  const int t = threadIdx.x;

  __shared__ int aidS[8];
  __shared__ float repS[8][256];      // 8 KB

  if (t < 8) aidS[t] = list[off + start + (t < n ? t : 0)];
  __syncthreads();

  // stage 8 rows x 256 floats = 512 quads; 2 iters x 256 thr; each wave = 1 full row (1KB, coalesced)
  #pragma unroll
  for (int it = 0; it < 2; ++it) {
    const int idx = it * 256 + t;
    const int row = idx >> 6;          // 64 quads per row -> wave-uniform row
    const int q   = idx & 63;
    *(float4*)&repS[row][q * 4] = *(const float4*)(rep + (size_t)aidS[row] * 256 + q * 4);
  }
  __syncthreads();

  const int pq = t & 31, jq = t >> 5;          // jq = atom 0..7
  const int p0 = pq * 4;
  const float* red_e = reductors + e * (REPD * NPCAS) + p0;

  float a0 = 0.0f, a1 = 0.0f, a2 = 0.0f, a3 = 0.0f;

  for (int r0 = 0; r0 < 256; r0 += 4) {
    const float4 rv0 = *(const float4*)(red_e + (r0 + 0) * 128);
    const float4 rv1 = *(const float4*)(red_e + (r0 + 1) * 128);
    const float4 rv2 = *(const float4*)(red_e + (r0 + 2) * 128);
    const float4 rv3 = *(const float4*)(red_e + (r0 + 3) * 128);
    const float4 q4  = *(const float4*)&repS[jq][r0];   // 2 distinct addrs/wave: free bcast
    a0 = fmaf(q4.w, rv3.x, fmaf(q4.z, rv2.x, fmaf(q4.y, rv1.x, fmaf(q4.x, rv0.x, a0))));
    a1 = fmaf(q4.w, rv3.y, fmaf(q4.z, rv2.y, fmaf(q4.y, rv1.y, fmaf(q4.x, rv0.y, a1))));
    a2 = fmaf(q4.w, rv3.z, fmaf(q4.z, rv2.z, fmaf(q4.y, rv1.z, fmaf(q4.x, rv0.z, a2))));
    a3 = fmaf(q4.w, rv3.w, fmaf(q4.z, rv2.w, fmaf(q4.y, rv1.w, fmaf(q4.x, rv0.w, a3))));
  }

  if (jq < n) {
    float4 v = make_float4(a0, a1, a2, a3);
    *(float4*)(sub + (size_t)(off + start + jq) * 128 + p0) = v;
  }
}

// ---------------- K2: verified R6 arithmetic, 1-wave blocks for TLP ----------------
template <int CTRL>
__device__ __forceinline__ float dppx(float x) {
  return __int_as_float(__builtin_amdgcn_update_dpp(0, __float_as_int(x), CTRL, 0xF, 0xF, true));
}
template <int OFF>
__device__ __forceinline__ float swzx(float x) {
  return __int_as_float(__builtin_amdgcn_ds_swizzle(__float_as_int(x), OFF));
}

#define BFLY_DPP(x, CTRL, sg) { float t_ = dppx<CTRL>(x); (x) = fmaf((x), (sg), t_); }
#define BFLY_SWZ(x, OFF, sg)  { float t_ = swzx<OFF>(x);  (x) = fmaf((x), (sg), t_); }

#define SWAP16(a, b) asm("v_permlane16_swap_b32 %0, %1" : "+v"(a), "+v"(b));
#define SWAP32(a, b) asm("v_permlane32_swap_b32 %0, %1" : "+v"(a), "+v"(b));
#define XST16(lo, hi) { SWAP16(lo, hi) float s_ = (lo) + (hi), d_ = (lo) - (hi); SWAP16(s_, d_) (lo) = s_; (hi) = d_; }
#define XST32(lo, hi) { SWAP32(lo, hi) float s_ = (lo) + (hi), d_ = (lo) - (hi); SWAP32(s_, d_) (lo) = s_; (hi) = d_; }

// xor1: quad_perm 0xB1; xor2: 0x4E; xor4: ds_swizzle; xor8: row_ror:8;
// xor16/xor32: permlane swap trick; bit6: register add/sub.
#define FW128(lo, hi) { \
  { float a_ = (lo) + (hi), b_ = (lo) - (hi); (lo) = a_; (hi) = b_; } \
  BFLY_DPP(lo, 0xB1, sg1)    BFLY_DPP(hi, 0xB1, sg1) \
  BFLY_DPP(lo, 0x4E, sg2)    BFLY_DPP(hi, 0x4E, sg2) \
  BFLY_SWZ(lo, 0x101F, sg4)  BFLY_SWZ(hi, 0x101F, sg4) \
  BFLY_DPP(lo, 0x128, sg8)   BFLY_DPP(hi, 0x128, sg8) \
  XST16(lo, hi) \
  XST32(lo, hi) }

__global__ __launch_bounds__(64) void k2_features(const float* __restrict__ sub,
                                                  const int* __restrict__ list,
                                                  const int* __restrict__ meta,
                                                  const int* __restrict__ Z,
                                                  const float* __restrict__ Dmat,
                                                  const float* __restrict__ bias,
                                                  const float* __restrict__ alpha,
                                                  float* __restrict__ out) {
  const int total = meta[8];
  const int lane = threadIdx.x & 63;
  const int pos0 = blockIdx.x * 4;
  if (pos0 >= total) return;
  const bool has1 = (pos0 + 1) < total;
  const bool has2 = (pos0 + 2) < total;
  const bool has3 = (pos0 + 3) < total;

  const float sg1 = (lane & 1) ? -1.0f : 1.0f;
  const float sg2 = (lane & 2) ? -1.0f : 1.0f;
  const float sg4 = (lane & 4) ? -1.0f : 1.0f;
  const float sg8 = (lane & 8) ? -1.0f : 1.0f;

  const int aid0 = list[pos0];
  const int e0 = elem_of(Z[aid0]);
  const float slo0 = sub[(size_t)pos0 * 128 + lane];
  const float shi0 = sub[(size_t)pos0 * 128 + 64 + lane];

  int aid1 = aid0, e1 = 0; float slo1 = 0.0f, shi1 = 0.0f;
  if (has1) {
    aid1 = list[pos0 + 1]; e1 = elem_of(Z[aid1]);
    slo1 = sub[(size_t)(pos0 + 1) * 128 + lane];
    shi1 = sub[(size_t)(pos0 + 1) * 128 + 64 + lane];
  }
  int aid2 = aid0, e2 = 0; float slo2 = 0.0f, shi2 = 0.0f;
  if (has2) {
    aid2 = list[pos0 + 2]; e2 = elem_of(Z[aid2]);
    slo2 = sub[(size_t)(pos0 + 2) * 128 + lane];
    shi2 = sub[(size_t)(pos0 + 2) * 128 + 64 + lane];
  }
  int aid3 = aid0, e3 = 0; float slo3 = 0.0f, shi3 = 0.0f;
  if (has3) {
    aid3 = list[pos0 + 3]; e3 = elem_of(Z[aid3]);
    slo3 = sub[(size_t)(pos0 + 3) * 128 + lane];
    shi3 = sub[(size_t)(pos0 + 3) * 128 + 64 + lane];
  }

  const float* De0 = Dmat + e0 * (2 * NSTACKS * NPCAS);
  const float* De1 = Dmat + e1 * (2 * NSTACKS * NPCAS);
  const float* De2 = Dmat + e2 * (2 * NSTACKS * NPCAS);
  const float* De3 = Dmat + e3 * (2 * NSTACKS * NPCAS);
  const float* be0 = bias + e0 * NFEAT;
  const float* be1 = bias + e1 * NFEAT;
  const float* be2 = bias + e2 * NFEAT;
  const float* be3 = bias + e3 * NFEAT;

  float acc0 = 0.0f, acc1 = 0.0f, acc2 = 0.0f, acc3 = 0.0f;

  for (int s = 0; s < NSTACKS; ++s) {
    const int s0 = s * 128, s1 = (NSTACKS + s) * 128;
    const float alo = alpha[s0 + lane], ahi = alpha[s0 + 64 + lane];

    float lo0 = slo0 * De0[s0 + lane], hi0 = shi0 * De0[s0 + 64 + lane];
    float lo1 = slo1 * De1[s0 + lane], hi1 = shi1 * De1[s0 + 64 + lane];
    float lo2 = slo2 * De2[s0 + lane], hi2 = shi2 * De2[s0 + 64 + lane];
    float lo3 = slo3 * De3[s0 + lane], hi3 = shi3 * De3[s0 + 64 + lane];

    FW128(lo0, hi0) FW128(lo1, hi1) FW128(lo2, hi2) FW128(lo3, hi3)

    lo0 *= De0[s1 + lane]; hi0 *= De0[s1 + 64 + lane];
    lo1 *= De1[s1 + lane]; hi1 *= De1[s1 + 64 + lane];
    lo2 *= De2[s1 + lane]; hi2 *= De2[s1 + 64 + lane];
    lo3 *= De3[s1 + lane]; hi3 *= De3[s1 + 64 + lane];

    FW128(lo0, hi0) FW128(lo1, hi1) FW128(lo2, hi2) FW128(lo3, hi3)

    acc0 = fmaf(__cosf(fmaf(lo0, SCALE_C, be0[s0 + lane])),      alo, acc0);
    acc0 = fmaf(__cosf(fmaf(hi0, SCALE_C, be0[s0 + 64 + lane])), ahi, acc0);
    acc1 = fmaf(__cosf(fmaf(lo1, SCALE_C, be1[s0 + lane])),      alo, acc1);
    acc1 = fmaf(__cosf(fmaf(hi1, SCALE_C, be1[s0 + 64 + lane])), ahi, acc1);
    acc2 = fmaf(__cosf(fmaf(lo2, SCALE_C, be2[s0 + lane])),      alo, acc2);
    acc2 = fmaf(__cosf(fmaf(hi2, SCALE_C, be2[s0 + 64 + lane])), ahi, acc2);
    acc3 = fmaf(__cosf(fmaf(lo3, SCALE_C, be3[s0 + lane])),      alo, acc3);
    acc3 = fmaf(__cosf(fmaf(hi3, SCALE_C, be3[s0 + 64 + lane])), ahi, acc3);
  }

  #pragma unroll
  for (int o = 32; o > 0; o >>= 1) {
    acc0 += __shfl_xor(acc0, o, 64);
    acc1 += __shfl_xor(acc1, o, 64);
    acc2 += __shfl_xor(acc2, o, 64);
    acc3 += __shfl_xor(acc3, o, 64);
  }
  if (lane == 0)         atomicAdd(out + (aid0 >> 5), acc0 * FEATN_C);
  if (lane == 1 && has1) atomicAdd(out + (aid1 >> 5), acc1 * FEATN_C);
  if (lane == 2 && has2) atomicAdd(out + (aid2 >> 5), acc2 * FEATN_C);
  if (lane == 3 && has3) atomicAdd(out + (aid3 >> 5), acc3 * FEATN_C);
}

extern "C" void kernel_launch(void* const* d_in, const int* in_sizes, int n_in,
                              void* d_out, int out_size, void* d_ws, size_t ws_size,
                              hipStream_t stream) {
  const float* rep       = (const float*)d_in[0];
  const int*   Z         = (const int*)  d_in[1];
  const float* reductors = (const float*)d_in[2];
  const float* Dmat      = (const float*)d_in[3];
  const float* bias      = (const float*)d_in[4];
  const float* alpha     = (const float*)d_in[5];
  float* out = (float*)d_out;

  char* wsb = (char*)d_ws;
  int*   list = (int*)(wsb + LIST_OFF);
  int*   meta = (int*)(wsb + META_OFF);
  float* sub  = (float*)(wsb + SUB_OFF);

  k0_bucket<<<1, 256, 0, stream>>>(Z, list, meta, out);
  dim3 g1(1024, 4);                      // 8-atom tiles; covers cnt up to 8192
  k1_matvec<<<g1, 256, 0, stream>>>(rep, reductors, list, meta, sub);
  k2_features<<<2048, 64, 0, stream>>>(sub, list, meta, Z, Dmat, bias, alpha, out);
}

// Round 8
// 90.043 us; speedup vs baseline: 1.1559x; 1.1559x over previous
//
#include <hip/hip_runtime.h>

// Problem constants
#define NMOLS   256
#define NATOMS  32
#define REPD    256
#define NPCAS   128
#define NSTACKS 32
#define NFEAT   4096
#define NELEM   4

// ws layout (bytes)
#define LIST_OFF 0          // int list[8192]
#define META_OFF 32768      // int meta[16]
#define SUB_OFF  40960      // float sub[8192*128]

#define SCALE_C 0.029462782549439476f   // sqrt(128)/(3*128)
#define FEATN_C 0.022097086912079608f   // sqrt(2/4096)

__device__ __forceinline__ int elem_of(int z) {
  return (z == 1) ? 0 : (z == 6) ? 1 : (z == 7) ? 2 : (z == 8) ? 3 : -1;
}

// ---------------- K0: bucket atoms by element (deterministic), zero out ----------------
__global__ __launch_bounds__(256) void k0_bucket(const int* __restrict__ Z,
                                                 int* __restrict__ list,
                                                 int* __restrict__ meta,
                                                 float* __restrict__ out) {
  __shared__ int4 cntS[256];
  const int t = threadIdx.x;
  out[t] = 0.0f;
  int c0 = 0, c1 = 0, c2 = 0, c3 = 0;
  #pragma unroll
  for (int k = 0; k < 32; ++k) {
    const int z = Z[k * 256 + t];
    c0 += (z == 1); c1 += (z == 6); c2 += (z == 7); c3 += (z == 8);
  }
  int4 v = make_int4(c0, c1, c2, c3);
  cntS[t] = v;
  __syncthreads();
  for (int step = 1; step < 256; step <<= 1) {
    int4 add = make_int4(0, 0, 0, 0);
    if (t >= step) add = cntS[t - step];
    __syncthreads();
    v.x += add.x; v.y += add.y; v.z += add.z; v.w += add.w;
    cntS[t] = v;
    __syncthreads();
  }
  const int4 tot = cntS[255];
  int o0 = v.x - c0;
  int o1 = tot.x + v.y - c1;
  int o2 = tot.x + tot.y + v.z - c2;
  int o3 = tot.x + tot.y + tot.z + v.w - c3;
  #pragma unroll
  for (int k = 0; k < 32; ++k) {
    const int a = k * 256 + t;
    const int z = Z[a];
    if      (z == 1) list[o0++] = a;
    else if (z == 6) list[o1++] = a;
    else if (z == 7) list[o2++] = a;
    else if (z == 8) list[o3++] = a;
  }
  if (t == 0) {
    meta[0] = tot.x; meta[1] = tot.y; meta[2] = tot.z; meta[3] = tot.w;
    meta[4] = 0;
    meta[5] = tot.x;
    meta[6] = tot.x + tot.y;
    meta[7] = tot.x + tot.y + tot.z;
    meta[8] = tot.x + tot.y + tot.z + tot.w;
  }
}

// ---------------- K1: register-tiled matvec (verbatim R3 verified version) ----------------
__global__ __launch_bounds__(256) void k1_matvec(const float* __restrict__ rep,
                                                 const float* __restrict__ reductors,
                                                 const int* __restrict__ list,
                                                 const int* __restrict__ meta,
                                                 float* __restrict__ sub) {
  const int e = blockIdx.y;
  const int cnt = meta[e];
  const int off = meta[4 + e];
  const int start = blockIdx.x * 64;
  if (start >= cnt) return;
  const int n = min(64, cnt - start);
  const int t = threadIdx.x;

  __shared__ int aidS[64];
  __shared__ float repS[64][128];     // 32 KB, one K-half at a time

  if (t < 64) aidS[t] = list[off + start + (t < n ? t : 0)];

  const int pq = t & 31, jq = t >> 5;
  const int p0 = pq * 4, j0 = jq * 8;
  const float* red_e = reductors + e * (REPD * NPCAS);

  float acc[8][4];
  #pragma unroll
  for (int j = 0; j < 8; ++j)
    #pragma unroll
    for (int q = 0; q < 4; ++q) acc[j][q] = 0.0f;

  for (int kh = 0; kh < 2; ++kh) {
    __syncthreads();
    #pragma unroll
    for (int it = 0; it < 8; ++it) {
      const int idx = it * 256 + t;
      const int row = idx >> 5;          // 32 quads per row
      const int q   = idx & 31;
      *(float4*)&repS[row][q * 4] =
          *(const float4*)(rep + (size_t)aidS[row] * 256 + kh * 128 + q * 4);
    }
    __syncthreads();

    const float* redk = red_e + (kh * 128) * 128 + p0;
    for (int r0 = 0; r0 < 128; r0 += 4) {
      const float4 rv0 = *(const float4*)(redk + (r0 + 0) * 128);
      const float4 rv1 = *(const float4*)(redk + (r0 + 1) * 128);
      const float4 rv2 = *(const float4*)(redk + (r0 + 2) * 128);
      const float4 rv3 = *(const float4*)(redk + (r0 + 3) * 128);
      float4 rp[8];
      #pragma unroll
      for (int j = 0; j < 8; ++j)
        rp[j] = *(const float4*)&repS[j0 + j][r0];
      #pragma unroll
      for (int j = 0; j < 8; ++j) {
        acc[j][0] = fmaf(rp[j].w, rv3.x, fmaf(rp[j].z, rv2.x, fmaf(rp[j].y, rv1.x, fmaf(rp[j].x, rv0.x, acc[j][0]))));
        acc[j][1] = fmaf(rp[j].w, rv3.y, fmaf(rp[j].z, rv2.y, fmaf(rp[j].y, rv1.y, fmaf(rp[j].x, rv0.y, acc[j][1]))));
        acc[j][2] = fmaf(rp[j].w, rv3.z, fmaf(rp[j].z, rv2.z, fmaf(rp[j].y, rv1.z, fmaf(rp[j].x, rv0.z, acc[j][2]))));
        acc[j][3] = fmaf(rp[j].w, rv3.w, fmaf(rp[j].z, rv2.w, fmaf(rp[j].y, rv1.w, fmaf(rp[j].x, rv0.w, acc[j][3]))));
      }
    }
  }

  #pragma unroll
  for (int j = 0; j < 8; ++j) {
    const int a = j0 + j;
    if (a < n) {
      float4 v = make_float4(acc[j][0], acc[j][1], acc[j][2], acc[j][3]);
      *(float4*)(sub + (size_t)(off + start + a) * 128 + p0) = v;
    }
  }
}

// ---------------- K2: verified arithmetic, stack-split x4 (wave = 4 atoms x 8 stacks) ----------------
template <int CTRL>
__device__ __forceinline__ float dppx(float x) {
  return __int_as_float(__builtin_amdgcn_update_dpp(0, __float_as_int(x), CTRL, 0xF, 0xF, true));
}
template <int OFF>
__device__ __forceinline__ float swzx(float x) {
  return __int_as_float(__builtin_amdgcn_ds_swizzle(__float_as_int(x), OFF));
}

#define BFLY_DPP(x, CTRL, sg) { float t_ = dppx<CTRL>(x); (x) = fmaf((x), (sg), t_); }
#define BFLY_SWZ(x, OFF, sg)  { float t_ = swzx<OFF>(x);  (x) = fmaf((x), (sg), t_); }

#define SWAP16(a, b) asm("v_permlane16_swap_b32 %0, %1" : "+v"(a), "+v"(b));
#define SWAP32(a, b) asm("v_permlane32_swap_b32 %0, %1" : "+v"(a), "+v"(b));
#define XST16(lo, hi) { SWAP16(lo, hi) float s_ = (lo) + (hi), d_ = (lo) - (hi); SWAP16(s_, d_) (lo) = s_; (hi) = d_; }
#define XST32(lo, hi) { SWAP32(lo, hi) float s_ = (lo) + (hi), d_ = (lo) - (hi); SWAP32(s_, d_) (lo) = s_; (hi) = d_; }

// xor1: quad_perm 0xB1; xor2: 0x4E; xor4: ds_swizzle; xor8: row_ror:8;
// xor16/xor32: permlane swap trick; bit6: register add/sub.
#define FW128(lo, hi) { \
  { float a_ = (lo) + (hi), b_ = (lo) - (hi); (lo) = a_; (hi) = b_; } \
  BFLY_DPP(lo, 0xB1, sg1)    BFLY_DPP(hi, 0xB1, sg1) \
  BFLY_DPP(lo, 0x4E, sg2)    BFLY_DPP(hi, 0x4E, sg2) \
  BFLY_SWZ(lo, 0x101F, sg4)  BFLY_SWZ(hi, 0x101F, sg4) \
  BFLY_DPP(lo, 0x128, sg8)   BFLY_DPP(hi, 0x128, sg8) \
  XST16(lo, hi) \
  XST32(lo, hi) }

__global__ __launch_bounds__(256) void k2_features(const float* __restrict__ sub,
                                                   const int* __restrict__ list,
                                                   const int* __restrict__ meta,
                                                   const int* __restrict__ Z,
                                                   const float* __restrict__ Dmat,
                                                   const float* __restrict__ bias,
                                                   const float* __restrict__ alpha,
                                                   float* __restrict__ out) {
  const int total = meta[8];
  const int w = threadIdx.x >> 6, lane = threadIdx.x & 63;
  const int pos0 = blockIdx.x * 4;             // block covers 4 positions, all 32 stacks
  if (pos0 >= total) return;
  const int sbeg = w * 8, send = sbeg + 8;     // this wave's 8 stacks
  const bool has1 = (pos0 + 1) < total;
  const bool has2 = (pos0 + 2) < total;
  const bool has3 = (pos0 + 3) < total;

  const float sg1 = (lane & 1) ? -1.0f : 1.0f;
  const float sg2 = (lane & 2) ? -1.0f : 1.0f;
  const float sg4 = (lane & 4) ? -1.0f : 1.0f;
  const float sg8 = (lane & 8) ? -1.0f : 1.0f;

  const int aid0 = list[pos0];
  const int e0 = elem_of(Z[aid0]);
  const float slo0 = sub[(size_t)pos0 * 128 + lane];
  const float shi0 = sub[(size_t)pos0 * 128 + 64 + lane];

  int aid1 = aid0, e1 = 0; float slo1 = 0.0f, shi1 = 0.0f;
  if (has1) {
    aid1 = list[pos0 + 1]; e1 = elem_of(Z[aid1]);
    slo1 = sub[(size_t)(pos0 + 1) * 128 + lane];
    shi1 = sub[(size_t)(pos0 + 1) * 128 + 64 + lane];
  }
  int aid2 = aid0, e2 = 0; float slo2 = 0.0f, shi2 = 0.0f;
  if (has2) {
    aid2 = list[pos0 + 2]; e2 = elem_of(Z[aid2]);
    slo2 = sub[(size_t)(pos0 + 2) * 128 + lane];
    shi2 = sub[(size_t)(pos0 + 2) * 128 + 64 + lane];
  }
  int aid3 = aid0, e3 = 0; float slo3 = 0.0f, shi3 = 0.0f;
  if (has3) {
    aid3 = list[pos0 + 3]; e3 = elem_of(Z[aid3]);
    slo3 = sub[(size_t)(pos0 + 3) * 128 + lane];
    shi3 = sub[(size_t)(pos0 + 3) * 128 + 64 + lane];
  }

  const float* De0 = Dmat + e0 * (2 * NSTACKS * NPCAS);
  const float* De1 = Dmat + e1 * (2 * NSTACKS * NPCAS);
  const float* De2 = Dmat + e2 * (2 * NSTACKS * NPCAS);
  const float* De3 = Dmat + e3 * (2 * NSTACKS * NPCAS);
  const float* be0 = bias + e0 * NFEAT;
  const float* be1 = bias + e1 * NFEAT;
  const float* be2 = bias + e2 * NFEAT;
  const float* be3 = bias + e3 * NFEAT;

  float acc0 = 0.0f, acc1 = 0.0f, acc2 = 0.0f, acc3 = 0.0f;

  for (int s = sbeg; s < send; ++s) {
    const int s0 = s * 128, s1 = (NSTACKS + s) * 128;
    const float alo = alpha[s0 + lane], ahi = alpha[s0 + 64 + lane];

    float lo0 = slo0 * De0[s0 + lane], hi0 = shi0 * De0[s0 + 64 + lane];
    float lo1 = slo1 * De1[s0 + lane], hi1 = shi1 * De1[s0 + 64 + lane];
    float lo2 = slo2 * De2[s0 + lane], hi2 = shi2 * De2[s0 + 64 + lane];
    float lo3 = slo3 * De3[s0 + lane], hi3 = shi3 * De3[s0 + 64 + lane];

    FW128(lo0, hi0) FW128(lo1, hi1) FW128(lo2, hi2) FW128(lo3, hi3)

    lo0 *= De0[s1 + lane]; hi0 *= De0[s1 + 64 + lane];
    lo1 *= De1[s1 + lane]; hi1 *= De1[s1 + 64 + lane];
    lo2 *= De2[s1 + lane]; hi2 *= De2[s1 + 64 + lane];
    lo3 *= De3[s1 + lane]; hi3 *= De3[s1 + 64 + lane];

    FW128(lo0, hi0) FW128(lo1, hi1) FW128(lo2, hi2) FW128(lo3, hi3)

    acc0 = fmaf(__cosf(fmaf(lo0, SCALE_C, be0[s0 + lane])),      alo, acc0);
    acc0 = fmaf(__cosf(fmaf(hi0, SCALE_C, be0[s0 + 64 + lane])), ahi, acc0);
    acc1 = fmaf(__cosf(fmaf(lo1, SCALE_C, be1[s0 + lane])),      alo, acc1);
    acc1 = fmaf(__cosf(fmaf(hi1, SCALE_C, be1[s0 + 64 + lane])), ahi, acc1);
    acc2 = fmaf(__cosf(fmaf(lo2, SCALE_C, be2[s0 + lane])),      alo, acc2);
    acc2 = fmaf(__cosf(fmaf(hi2, SCALE_C, be2[s0 + 64 + lane])), ahi, acc2);
    acc3 = fmaf(__cosf(fmaf(lo3, SCALE_C, be3[s0 + lane])),      alo, acc3);
    acc3 = fmaf(__cosf(fmaf(hi3, SCALE_C, be3[s0 + 64 + lane])), ahi, acc3);
  }

  #pragma unroll
  for (int o = 32; o > 0; o >>= 1) {
    acc0 += __shfl_xor(acc0, o, 64);
    acc1 += __shfl_xor(acc1, o, 64);
    acc2 += __shfl_xor(acc2, o, 64);
    acc3 += __shfl_xor(acc3, o, 64);
  }
  if (lane == 0)         atomicAdd(out + (aid0 >> 5), acc0 * FEATN_C);
  if (lane == 1 && has1) atomicAdd(out + (aid1 >> 5), acc1 * FEATN_C);
  if (lane == 2 && has2) atomicAdd(out + (aid2 >> 5), acc2 * FEATN_C);
  if (lane == 3 && has3) atomicAdd(out + (aid3 >> 5), acc3 * FEATN_C);
}

extern "C" void kernel_launch(void* const* d_in, const int* in_sizes, int n_in,
                              void* d_out, int out_size, void* d_ws, size_t ws_size,
                              hipStream_t stream) {
  const float* rep       = (const float*)d_in[0];
  const int*   Z         = (const int*)  d_in[1];
  const float* reductors = (const float*)d_in[2];
  const float* Dmat      = (const float*)d_in[3];
  const float* bias      = (const float*)d_in[4];
  const float* alpha     = (const float*)d_in[5];
  float* out = (float*)d_out;

  char* wsb = (char*)d_ws;
  int*   list = (int*)(wsb + LIST_OFF);
  int*   meta = (int*)(wsb + META_OFF);
  float* sub  = (float*)(wsb + SUB_OFF);

  k0_bucket<<<1, 256, 0, stream>>>(Z, list, meta, out);
  dim3 g1(32, 4);                        // 64-atom tiles (verified R3 config)
  k1_matvec<<<g1, 256, 0, stream>>>(rep, reductors, list, meta, sub);
  k2_features<<<2048, 256, 0, stream>>>(sub, list, meta, Z, Dmat, bias, alpha, out);
}

// Round 10
// 88.320 us; speedup vs baseline: 1.1784x; 1.0195x over previous
//
#include <hip/hip_runtime.h>

// Problem constants
#define NMOLS   256
#define NATOMS  32
#define REPD    256
#define NPCAS   128
#define NSTACKS 32
#define NFEAT   4096
#define NELEM   4

// ws layout (bytes)
#define LIST_OFF 0          // int list[8192]
#define META_OFF 32768      // int meta[16]
#define SUB_OFF  40960      // float sub[8192*128]

#define SCALE_C 0.029462782549439476f   // sqrt(128)/(3*128)
#define FEATN_C 0.022097086912079608f   // sqrt(2/4096)

__device__ __forceinline__ int elem_of(int z) {
  return (z == 1) ? 0 : (z == 6) ? 1 : (z == 7) ? 2 : (z == 8) ? 3 : -1;
}

// ---------------- K0: bucket atoms by element (deterministic), zero out ----------------
__global__ __launch_bounds__(256) void k0_bucket(const int* __restrict__ Z,
                                                 int* __restrict__ list,
                                                 int* __restrict__ meta,
                                                 float* __restrict__ out) {
  __shared__ int4 cntS[256];
  const int t = threadIdx.x;
  out[t] = 0.0f;
  int c0 = 0, c1 = 0, c2 = 0, c3 = 0;
  #pragma unroll
  for (int k = 0; k < 32; ++k) {
    const int z = Z[k * 256 + t];
    c0 += (z == 1); c1 += (z == 6); c2 += (z == 7); c3 += (z == 8);
  }
  int4 v = make_int4(c0, c1, c2, c3);
  cntS[t] = v;
  __syncthreads();
  for (int step = 1; step < 256; step <<= 1) {
    int4 add = make_int4(0, 0, 0, 0);
    if (t >= step) add = cntS[t - step];
    __syncthreads();
    v.x += add.x; v.y += add.y; v.z += add.z; v.w += add.w;
    cntS[t] = v;
    __syncthreads();
  }
  const int4 tot = cntS[255];
  int o0 = v.x - c0;
  int o1 = tot.x + v.y - c1;
  int o2 = tot.x + tot.y + v.z - c2;
  int o3 = tot.x + tot.y + tot.z + v.w - c3;
  #pragma unroll
  for (int k = 0; k < 32; ++k) {
    const int a = k * 256 + t;
    const int z = Z[a];
    if      (z == 1) list[o0++] = a;
    else if (z == 6) list[o1++] = a;
    else if (z == 7) list[o2++] = a;
    else if (z == 8) list[o3++] = a;
  }
  if (t == 0) {
    meta[0] = tot.x; meta[1] = tot.y; meta[2] = tot.z; meta[3] = tot.w;
    meta[4] = 0;
    meta[5] = tot.x;
    meta[6] = tot.x + tot.y;
    meta[7] = tot.x + tot.y + tot.z;
    meta[8] = tot.x + tot.y + tot.z + tot.w;
  }
}

// ---------------- K1: register-tiled matvec (verbatim R3 verified version) ----------------
__global__ __launch_bounds__(256) void k1_matvec(const float* __restrict__ rep,
                                                 const float* __restrict__ reductors,
                                                 const int* __restrict__ list,
                                                 const int* __restrict__ meta,
                                                 float* __restrict__ sub) {
  const int e = blockIdx.y;
  const int cnt = meta[e];
  const int off = meta[4 + e];
  const int start = blockIdx.x * 64;
  if (start >= cnt) return;
  const int n = min(64, cnt - start);
  const int t = threadIdx.x;

  __shared__ int aidS[64];
  __shared__ float repS[64][128];     // 32 KB, one K-half at a time

  if (t < 64) aidS[t] = list[off + start + (t < n ? t : 0)];

  const int pq = t & 31, jq = t >> 5;
  const int p0 = pq * 4, j0 = jq * 8;
  const float* red_e = reductors + e * (REPD * NPCAS);

  float acc[8][4];
  #pragma unroll
  for (int j = 0; j < 8; ++j)
    #pragma unroll
    for (int q = 0; q < 4; ++q) acc[j][q] = 0.0f;

  for (int kh = 0; kh < 2; ++kh) {
    __syncthreads();
    #pragma unroll
    for (int it = 0; it < 8; ++it) {
      const int idx = it * 256 + t;
      const int row = idx >> 5;          // 32 quads per row
      const int q   = idx & 31;
      *(float4*)&repS[row][q * 4] =
          *(const float4*)(rep + (size_t)aidS[row] * 256 + kh * 128 + q * 4);
    }
    __syncthreads();

    const float* redk = red_e + (kh * 128) * 128 + p0;
    for (int r0 = 0; r0 < 128; r0 += 4) {
      const float4 rv0 = *(const float4*)(redk + (r0 + 0) * 128);
      const float4 rv1 = *(const float4*)(redk + (r0 + 1) * 128);
      const float4 rv2 = *(const float4*)(redk + (r0 + 2) * 128);
      const float4 rv3 = *(const float4*)(redk + (r0 + 3) * 128);
      float4 rp[8];
      #pragma unroll
      for (int j = 0; j < 8; ++j)
        rp[j] = *(const float4*)&repS[j0 + j][r0];
      #pragma unroll
      for (int j = 0; j < 8; ++j) {
        acc[j][0] = fmaf(rp[j].w, rv3.x, fmaf(rp[j].z, rv2.x, fmaf(rp[j].y, rv1.x, fmaf(rp[j].x, rv0.x, acc[j][0]))));
        acc[j][1] = fmaf(rp[j].w, rv3.y, fmaf(rp[j].z, rv2.y, fmaf(rp[j].y, rv1.y, fmaf(rp[j].x, rv0.y, acc[j][1]))));
        acc[j][2] = fmaf(rp[j].w, rv3.z, fmaf(rp[j].z, rv2.z, fmaf(rp[j].y, rv1.z, fmaf(rp[j].x, rv0.z, acc[j][2]))));
        acc[j][3] = fmaf(rp[j].w, rv3.w, fmaf(rp[j].z, rv2.w, fmaf(rp[j].y, rv1.w, fmaf(rp[j].x, rv0.w, acc[j][3]))));
      }
    }
  }

  #pragma unroll
  for (int j = 0; j < 8; ++j) {
    const int a = j0 + j;
    if (a < n) {
      float4 v = make_float4(acc[j][0], acc[j][1], acc[j][2], acc[j][3]);
      *(float4*)(sub + (size_t)(off + start + a) * 128 + p0) = v;
    }
  }
}

// ---------------- K2: stack-split x4, uniform-element fast path, HAZARD-SAFE swaps ----------------
template <int CTRL>
__device__ __forceinline__ float dppx(float x) {
  return __int_as_float(__builtin_amdgcn_update_dpp(0, __float_as_int(x), CTRL, 0xF, 0xF, true));
}
template <int OFF>
__device__ __forceinline__ float swzx(float x) {
  return __int_as_float(__builtin_amdgcn_ds_swizzle(__float_as_int(x), OFF));
}

// Hazard-safe permlane swaps. Raw `asm("v_permlane16_swap_b32")` is opaque to the
// GCN hazard recognizer (VALU->DPP-source wait states are the programmer's job) and
// was schedule-dependently corrupting data (R4/R5/R9 failures). The gfx950 builtins
// are compiler-modeled, so hazards are inserted correctly.
__device__ __forceinline__ void swap16f(float& a, float& b) {
#if __has_builtin(__builtin_amdgcn_permlane16_swap)
  auto r = __builtin_amdgcn_permlane16_swap(__float_as_uint(a), __float_as_uint(b), false, false);
  a = __uint_as_float(r[0]);
  b = __uint_as_float(r[1]);
#else
  asm volatile("s_nop 1\n\tv_permlane16_swap_b32 %0, %1\n\ts_nop 1" : "+v"(a), "+v"(b));
#endif
}
__device__ __forceinline__ void swap32f(float& a, float& b) {
#if __has_builtin(__builtin_amdgcn_permlane32_swap)
  auto r = __builtin_amdgcn_permlane32_swap(__float_as_uint(a), __float_as_uint(b), false, false);
  a = __uint_as_float(r[0]);
  b = __uint_as_float(r[1]);
#else
  asm volatile("s_nop 1\n\tv_permlane32_swap_b32 %0, %1\n\ts_nop 1" : "+v"(a), "+v"(b));
#endif
}

#define BFLY_DPP(x, CTRL, sg) { float t_ = dppx<CTRL>(x); (x) = fmaf((x), (sg), t_); }
#define BFLY_SWZ(x, OFF, sg)  { float t_ = swzx<OFF>(x);  (x) = fmaf((x), (sg), t_); }

#define XST16(lo, hi) { swap16f(lo, hi); float s_ = (lo) + (hi), d_ = (lo) - (hi); swap16f(s_, d_); (lo) = s_; (hi) = d_; }
#define XST32(lo, hi) { swap32f(lo, hi); float s_ = (lo) + (hi), d_ = (lo) - (hi); swap32f(s_, d_); (lo) = s_; (hi) = d_; }

// xor1: quad_perm 0xB1; xor2: 0x4E; xor4: ds_swizzle; xor8: row_ror:8;
// xor16/xor32: permlane swap trick; bit6: register add/sub.
#define FW128(lo, hi) { \
  { float a_ = (lo) + (hi), b_ = (lo) - (hi); (lo) = a_; (hi) = b_; } \
  BFLY_DPP(lo, 0xB1, sg1)    BFLY_DPP(hi, 0xB1, sg1) \
  BFLY_DPP(lo, 0x4E, sg2)    BFLY_DPP(hi, 0x4E, sg2) \
  BFLY_SWZ(lo, 0x101F, sg4)  BFLY_SWZ(hi, 0x101F, sg4) \
  BFLY_DPP(lo, 0x128, sg8)   BFLY_DPP(hi, 0x128, sg8) \
  XST16(lo, hi) \
  XST32(lo, hi) }

__global__ __launch_bounds__(256) void k2_features(const float* __restrict__ sub,
                                                   const int* __restrict__ list,
                                                   const int* __restrict__ meta,
                                                   const int* __restrict__ Z,
                                                   const float* __restrict__ Dmat,
                                                   const float* __restrict__ bias,
                                                   const float* __restrict__ alpha,
                                                   float* __restrict__ out) {
  const int total = meta[8];
  const int w = threadIdx.x >> 6, lane = threadIdx.x & 63;
  const int pos0 = blockIdx.x * 4;             // block covers 4 positions, all 32 stacks
  if (pos0 >= total) return;
  const int sbeg = w * 8, send = sbeg + 8;     // this wave's 8 stacks
  const bool has1 = (pos0 + 1) < total;
  const bool has2 = (pos0 + 2) < total;
  const bool has3 = (pos0 + 3) < total;

  const float sg1 = (lane & 1) ? -1.0f : 1.0f;
  const float sg2 = (lane & 2) ? -1.0f : 1.0f;
  const float sg4 = (lane & 4) ? -1.0f : 1.0f;
  const float sg8 = (lane & 8) ? -1.0f : 1.0f;

  const int aid0 = list[pos0];
  const int e0 = elem_of(Z[aid0]);
  const float slo0 = sub[(size_t)pos0 * 128 + lane];
  const float shi0 = sub[(size_t)pos0 * 128 + 64 + lane];

  int aid1 = aid0, e1 = e0; float slo1 = 0.0f, shi1 = 0.0f;
  if (has1) {
    aid1 = list[pos0 + 1]; e1 = elem_of(Z[aid1]);
    slo1 = sub[(size_t)(pos0 + 1) * 128 + lane];
    shi1 = sub[(size_t)(pos0 + 1) * 128 + 64 + lane];
  }
  int aid2 = aid0, e2 = e0; float slo2 = 0.0f, shi2 = 0.0f;
  if (has2) {
    aid2 = list[pos0 + 2]; e2 = elem_of(Z[aid2]);
    slo2 = sub[(size_t)(pos0 + 2) * 128 + lane];
    shi2 = sub[(size_t)(pos0 + 2) * 128 + 64 + lane];
  }
  int aid3 = aid0, e3 = e0; float slo3 = 0.0f, shi3 = 0.0f;
  if (has3) {
    aid3 = list[pos0 + 3]; e3 = elem_of(Z[aid3]);
    slo3 = sub[(size_t)(pos0 + 3) * 128 + lane];
    shi3 = sub[(size_t)(pos0 + 3) * 128 + 64 + lane];
  }

  const float* De0 = Dmat + e0 * (2 * NSTACKS * NPCAS);
  const float* be0 = bias + e0 * NFEAT;

  float acc0 = 0.0f, acc1 = 0.0f, acc2 = 0.0f, acc3 = 0.0f;

  if (e0 == e1 && e1 == e2 && e2 == e3) {
    // -------- fast path: one coefficient set feeds all 4 chains --------
    for (int s = sbeg; s < send; ++s) {
      const int s0 = s * 128, s1 = (NSTACKS + s) * 128;
      const float d0lo = De0[s0 + lane], d0hi = De0[s0 + 64 + lane];
      const float d1lo = De0[s1 + lane], d1hi = De0[s1 + 64 + lane];
      const float blo  = be0[s0 + lane], bhi  = be0[s0 + 64 + lane];
      const float alo  = alpha[s0 + lane], ahi = alpha[s0 + 64 + lane];

      float lo0 = slo0 * d0lo, hi0 = shi0 * d0hi;
      float lo1 = slo1 * d0lo, hi1 = shi1 * d0hi;
      float lo2 = slo2 * d0lo, hi2 = shi2 * d0hi;
      float lo3 = slo3 * d0lo, hi3 = shi3 * d0hi;

      FW128(lo0, hi0) FW128(lo1, hi1) FW128(lo2, hi2) FW128(lo3, hi3)

      lo0 *= d1lo; hi0 *= d1hi;
      lo1 *= d1lo; hi1 *= d1hi;
      lo2 *= d1lo; hi2 *= d1hi;
      lo3 *= d1lo; hi3 *= d1hi;

      FW128(lo0, hi0) FW128(lo1, hi1) FW128(lo2, hi2) FW128(lo3, hi3)

      acc0 = fmaf(__cosf(fmaf(lo0, SCALE_C, blo)), alo, acc0);
      acc0 = fmaf(__cosf(fmaf(hi0, SCALE_C, bhi)), ahi, acc0);
      acc1 = fmaf(__cosf(fmaf(lo1, SCALE_C, blo)), alo, acc1);
      acc1 = fmaf(__cosf(fmaf(hi1, SCALE_C, bhi)), ahi, acc1);
      acc2 = fmaf(__cosf(fmaf(lo2, SCALE_C, blo)), alo, acc2);
      acc2 = fmaf(__cosf(fmaf(hi2, SCALE_C, bhi)), ahi, acc2);
      acc3 = fmaf(__cosf(fmaf(lo3, SCALE_C, blo)), alo, acc3);
      acc3 = fmaf(__cosf(fmaf(hi3, SCALE_C, bhi)), ahi, acc3);
    }
  } else {
    // -------- mixed-element fallback: per-chain loads (verified R8 body) --------
    const float* De1 = Dmat + e1 * (2 * NSTACKS * NPCAS);
    const float* De2 = Dmat + e2 * (2 * NSTACKS * NPCAS);
    const float* De3 = Dmat + e3 * (2 * NSTACKS * NPCAS);
    const float* be1 = bias + e1 * NFEAT;
    const float* be2 = bias + e2 * NFEAT;
    const float* be3 = bias + e3 * NFEAT;

    for (int s = sbeg; s < send; ++s) {
      const int s0 = s * 128, s1 = (NSTACKS + s) * 128;
      const float alo = alpha[s0 + lane], ahi = alpha[s0 + 64 + lane];

      float lo0 = slo0 * De0[s0 + lane], hi0 = shi0 * De0[s0 + 64 + lane];
      float lo1 = slo1 * De1[s0 + lane], hi1 = shi1 * De1[s0 + 64 + lane];
      float lo2 = slo2 * De2[s0 + lane], hi2 = shi2 * De2[s0 + 64 + lane];
      float lo3 = slo3 * De3[s0 + lane], hi3 = shi3 * De3[s0 + 64 + lane];

      FW128(lo0, hi0) FW128(lo1, hi1) FW128(lo2, hi2) FW128(lo3, hi3)

      lo0 *= De0[s1 + lane]; hi0 *= De0[s1 + 64 + lane];
      lo1 *= De1[s1 + lane]; hi1 *= De1[s1 + 64 + lane];
      lo2 *= De2[s1 + lane]; hi2 *= De2[s1 + 64 + lane];
      lo3 *= De3[s1 + lane]; hi3 *= De3[s1 + 64 + lane];

      FW128(lo0, hi0) FW128(lo1, hi1) FW128(lo2, hi2) FW128(lo3, hi3)

      acc0 = fmaf(__cosf(fmaf(lo0, SCALE_C, be0[s0 + lane])),      alo, acc0);
      acc0 = fmaf(__cosf(fmaf(hi0, SCALE_C, be0[s0 + 64 + lane])), ahi, acc0);
      acc1 = fmaf(__cosf(fmaf(lo1, SCALE_C, be1[s0 + lane])),      alo, acc1);
      acc1 = fmaf(__cosf(fmaf(hi1, SCALE_C, be1[s0 + 64 + lane])), ahi, acc1);
      acc2 = fmaf(__cosf(fmaf(lo2, SCALE_C, be2[s0 + lane])),      alo, acc2);
      acc2 = fmaf(__cosf(fmaf(hi2, SCALE_C, be2[s0 + 64 + lane])), ahi, acc2);
      acc3 = fmaf(__cosf(fmaf(lo3, SCALE_C, be3[s0 + lane])),      alo, acc3);
      acc3 = fmaf(__cosf(fmaf(hi3, SCALE_C, be3[s0 + 64 + lane])), ahi, acc3);
    }
  }

  #pragma unroll
  for (int o = 32; o > 0; o >>= 1) {
    acc0 += __shfl_xor(acc0, o, 64);
    acc1 += __shfl_xor(acc1, o, 64);
    acc2 += __shfl_xor(acc2, o, 64);
    acc3 += __shfl_xor(acc3, o, 64);
  }
  if (lane == 0)         atomicAdd(out + (aid0 >> 5), acc0 * FEATN_C);
  if (lane == 1 && has1) atomicAdd(out + (aid1 >> 5), acc1 * FEATN_C);
  if (lane == 2 && has2) atomicAdd(out + (aid2 >> 5), acc2 * FEATN_C);
  if (lane == 3 && has3) atomicAdd(out + (aid3 >> 5), acc3 * FEATN_C);
}

extern "C" void kernel_launch(void* const* d_in, const int* in_sizes, int n_in,
                              void* d_out, int out_size, void* d_ws, size_t ws_size,
                              hipStream_t stream) {
  const float* rep       = (const float*)d_in[0];
  const int*   Z         = (const int*)  d_in[1];
  const float* reductors = (const float*)d_in[2];
  const float* Dmat      = (const float*)d_in[3];
  const float* bias      = (const float*)d_in[4];
  const float* alpha     = (const float*)d_in[5];
  float* out = (float*)d_out;

  char* wsb = (char*)d_ws;
  int*   list = (int*)(wsb + LIST_OFF);
  int*   meta = (int*)(wsb + META_OFF);
  float* sub  = (float*)(wsb + SUB_OFF);

  k0_bucket<<<1, 256, 0, stream>>>(Z, list, meta, out);
  dim3 g1(32, 4);                        // 64-atom tiles (verified R3 config)
  k1_matvec<<<g1, 256, 0, stream>>>(rep, reductors, list, meta, sub);
  k2_features<<<2048, 256, 0, stream>>>(sub, list, meta, Z, Dmat, bias, alpha, out);
}

// Round 11
// 87.437 us; speedup vs baseline: 1.1903x; 1.0101x over previous
//
#include <hip/hip_runtime.h>

// Problem constants
#define NMOLS   256
#define NATOMS  32
#define REPD    256
#define NPCAS   128
#define NSTACKS 32
#define NFEAT   4096
#define NELEM   4

// ws layout (bytes)
#define LIST_OFF 0          // int list[8192]
#define META_OFF 32768      // int meta[16]
#define SUB_OFF  40960      // float sub[8192*128]

#define SCALE_C 0.029462782549439476f   // sqrt(128)/(3*128)
#define FEATN_C 0.022097086912079608f   // sqrt(2/4096)

__device__ __forceinline__ int elem_of(int z) {
  return (z == 1) ? 0 : (z == 6) ? 1 : (z == 7) ? 2 : (z == 8) ? 3 : -1;
}

// ---------------- K0: bucket atoms by element (deterministic), zero out ----------------
__global__ __launch_bounds__(256) void k0_bucket(const int* __restrict__ Z,
                                                 int* __restrict__ list,
                                                 int* __restrict__ meta,
                                                 float* __restrict__ out) {
  __shared__ int4 cntS[256];
  const int t = threadIdx.x;
  out[t] = 0.0f;
  int c0 = 0, c1 = 0, c2 = 0, c3 = 0;
  #pragma unroll
  for (int k = 0; k < 32; ++k) {
    const int z = Z[k * 256 + t];
    c0 += (z == 1); c1 += (z == 6); c2 += (z == 7); c3 += (z == 8);
  }
  int4 v = make_int4(c0, c1, c2, c3);
  cntS[t] = v;
  __syncthreads();
  for (int step = 1; step < 256; step <<= 1) {
    int4 add = make_int4(0, 0, 0, 0);
    if (t >= step) add = cntS[t - step];
    __syncthreads();
    v.x += add.x; v.y += add.y; v.z += add.z; v.w += add.w;
    cntS[t] = v;
    __syncthreads();
  }
  const int4 tot = cntS[255];
  int o0 = v.x - c0;
  int o1 = tot.x + v.y - c1;
  int o2 = tot.x + tot.y + v.z - c2;
  int o3 = tot.x + tot.y + tot.z + v.w - c3;
  #pragma unroll
  for (int k = 0; k < 32; ++k) {
    const int a = k * 256 + t;
    const int z = Z[a];
    if      (z == 1) list[o0++] = a;
    else if (z == 6) list[o1++] = a;
    else if (z == 7) list[o2++] = a;
    else if (z == 8) list[o3++] = a;
  }
  if (t == 0) {
    meta[0] = tot.x; meta[1] = tot.y; meta[2] = tot.z; meta[3] = tot.w;
    meta[4] = 0;
    meta[5] = tot.x;
    meta[6] = tot.x + tot.y;
    meta[7] = tot.x + tot.y + tot.z;
    meta[8] = tot.x + tot.y + tot.z + tot.w;
  }
}

// ---------------- K1: register-tiled matvec (verbatim R3 verified version) ----------------
__global__ __launch_bounds__(256) void k1_matvec(const float* __restrict__ rep,
                                                 const float* __restrict__ reductors,
                                                 const int* __restrict__ list,
                                                 const int* __restrict__ meta,
                                                 float* __restrict__ sub) {
  const int e = blockIdx.y;
  const int cnt = meta[e];
  const int off = meta[4 + e];
  const int start = blockIdx.x * 64;
  if (start >= cnt) return;
  const int n = min(64, cnt - start);
  const int t = threadIdx.x;

  __shared__ int aidS[64];
  __shared__ float repS[64][128];     // 32 KB, one K-half at a time

  if (t < 64) aidS[t] = list[off + start + (t < n ? t : 0)];

  const int pq = t & 31, jq = t >> 5;
  const int p0 = pq * 4, j0 = jq * 8;
  const float* red_e = reductors + e * (REPD * NPCAS);

  float acc[8][4];
  #pragma unroll
  for (int j = 0; j < 8; ++j)
    #pragma unroll
    for (int q = 0; q < 4; ++q) acc[j][q] = 0.0f;

  for (int kh = 0; kh < 2; ++kh) {
    __syncthreads();
    #pragma unroll
    for (int it = 0; it < 8; ++it) {
      const int idx = it * 256 + t;
      const int row = idx >> 5;          // 32 quads per row
      const int q   = idx & 31;
      *(float4*)&repS[row][q * 4] =
          *(const float4*)(rep + (size_t)aidS[row] * 256 + kh * 128 + q * 4);
    }
    __syncthreads();

    const float* redk = red_e + (kh * 128) * 128 + p0;
    for (int r0 = 0; r0 < 128; r0 += 4) {
      const float4 rv0 = *(const float4*)(redk + (r0 + 0) * 128);
      const float4 rv1 = *(const float4*)(redk + (r0 + 1) * 128);
      const float4 rv2 = *(const float4*)(redk + (r0 + 2) * 128);
      const float4 rv3 = *(const float4*)(redk + (r0 + 3) * 128);
      float4 rp[8];
      #pragma unroll
      for (int j = 0; j < 8; ++j)
        rp[j] = *(const float4*)&repS[j0 + j][r0];
      #pragma unroll
      for (int j = 0; j < 8; ++j) {
        acc[j][0] = fmaf(rp[j].w, rv3.x, fmaf(rp[j].z, rv2.x, fmaf(rp[j].y, rv1.x, fmaf(rp[j].x, rv0.x, acc[j][0]))));
        acc[j][1] = fmaf(rp[j].w, rv3.y, fmaf(rp[j].z, rv2.y, fmaf(rp[j].y, rv1.y, fmaf(rp[j].x, rv0.y, acc[j][1]))));
        acc[j][2] = fmaf(rp[j].w, rv3.z, fmaf(rp[j].z, rv2.z, fmaf(rp[j].y, rv1.z, fmaf(rp[j].x, rv0.z, acc[j][2]))));
        acc[j][3] = fmaf(rp[j].w, rv3.w, fmaf(rp[j].z, rv2.w, fmaf(rp[j].y, rv1.w, fmaf(rp[j].x, rv0.w, acc[j][3]))));
      }
    }
  }

  #pragma unroll
  for (int j = 0; j < 8; ++j) {
    const int a = j0 + j;
    if (a < n) {
      float4 v = make_float4(acc[j][0], acc[j][1], acc[j][2], acc[j][3]);
      *(float4*)(sub + (size_t)(off + start + a) * 128 + p0) = v;
    }
  }
}

// ---------------- K2: stack-split x4, STAGE-INTERLEAVED 4-chain FWHT ----------------
template <int CTRL>
__device__ __forceinline__ float dppx(float x) {
  return __int_as_float(__builtin_amdgcn_update_dpp(0, __float_as_int(x), CTRL, 0xF, 0xF, true));
}
template <int OFF>
__device__ __forceinline__ float swzx(float x) {
  return __int_as_float(__builtin_amdgcn_ds_swizzle(__float_as_int(x), OFF));
}

// Hazard-safe permlane swaps (builtins are compiler-modeled; raw asm corrupted data
// schedule-dependently in R4/R5/R9 — keep builtins).
__device__ __forceinline__ void swap16f(float& a, float& b) {
#if __has_builtin(__builtin_amdgcn_permlane16_swap)
  auto r = __builtin_amdgcn_permlane16_swap(__float_as_uint(a), __float_as_uint(b), false, false);
  a = __uint_as_float(r[0]);
  b = __uint_as_float(r[1]);
#else
  asm volatile("s_nop 1\n\tv_permlane16_swap_b32 %0, %1\n\ts_nop 1" : "+v"(a), "+v"(b));
#endif
}
__device__ __forceinline__ void swap32f(float& a, float& b) {
#if __has_builtin(__builtin_amdgcn_permlane32_swap)
  auto r = __builtin_amdgcn_permlane32_swap(__float_as_uint(a), __float_as_uint(b), false, false);
  a = __uint_as_float(r[0]);
  b = __uint_as_float(r[1]);
#else
  asm volatile("s_nop 1\n\tv_permlane32_swap_b32 %0, %1\n\ts_nop 1" : "+v"(a), "+v"(b));
#endif
}

// Stage-interleaved 4-chain FW128: same per-chain op sequence as the verified FW128
// (bitwise-identical results), but all 4 chains advance stage-by-stage so the
// scheduler gets 8-wide ILP and the 8 ds_swizzles share one wait window.
#define FW128X4(L0,H0,L1,H1,L2,H2,L3,H3) { \
  { float aa_; \
    aa_ = L0 + H0; H0 = L0 - H0; L0 = aa_; \
    aa_ = L1 + H1; H1 = L1 - H1; L1 = aa_; \
    aa_ = L2 + H2; H2 = L2 - H2; L2 = aa_; \
    aa_ = L3 + H3; H3 = L3 - H3; L3 = aa_; } \
  { float t0_ = dppx<0xB1>(L0), t1_ = dppx<0xB1>(H0), t2_ = dppx<0xB1>(L1), t3_ = dppx<0xB1>(H1); \
    float t4_ = dppx<0xB1>(L2), t5_ = dppx<0xB1>(H2), t6_ = dppx<0xB1>(L3), t7_ = dppx<0xB1>(H3); \
    L0 = fmaf(L0, sg1, t0_); H0 = fmaf(H0, sg1, t1_); L1 = fmaf(L1, sg1, t2_); H1 = fmaf(H1, sg1, t3_); \
    L2 = fmaf(L2, sg1, t4_); H2 = fmaf(H2, sg1, t5_); L3 = fmaf(L3, sg1, t6_); H3 = fmaf(H3, sg1, t7_); } \
  { float t0_ = dppx<0x4E>(L0), t1_ = dppx<0x4E>(H0), t2_ = dppx<0x4E>(L1), t3_ = dppx<0x4E>(H1); \
    float t4_ = dppx<0x4E>(L2), t5_ = dppx<0x4E>(H2), t6_ = dppx<0x4E>(L3), t7_ = dppx<0x4E>(H3); \
    L0 = fmaf(L0, sg2, t0_); H0 = fmaf(H0, sg2, t1_); L1 = fmaf(L1, sg2, t2_); H1 = fmaf(H1, sg2, t3_); \
    L2 = fmaf(L2, sg2, t4_); H2 = fmaf(H2, sg2, t5_); L3 = fmaf(L3, sg2, t6_); H3 = fmaf(H3, sg2, t7_); } \
  { float t0_ = swzx<0x101F>(L0), t1_ = swzx<0x101F>(H0), t2_ = swzx<0x101F>(L1), t3_ = swzx<0x101F>(H1); \
    float t4_ = swzx<0x101F>(L2), t5_ = swzx<0x101F>(H2), t6_ = swzx<0x101F>(L3), t7_ = swzx<0x101F>(H3); \
    L0 = fmaf(L0, sg4, t0_); H0 = fmaf(H0, sg4, t1_); L1 = fmaf(L1, sg4, t2_); H1 = fmaf(H1, sg4, t3_); \
    L2 = fmaf(L2, sg4, t4_); H2 = fmaf(H2, sg4, t5_); L3 = fmaf(L3, sg4, t6_); H3 = fmaf(H3, sg4, t7_); } \
  { float t0_ = dppx<0x128>(L0), t1_ = dppx<0x128>(H0), t2_ = dppx<0x128>(L1), t3_ = dppx<0x128>(H1); \
    float t4_ = dppx<0x128>(L2), t5_ = dppx<0x128>(H2), t6_ = dppx<0x128>(L3), t7_ = dppx<0x128>(H3); \
    L0 = fmaf(L0, sg8, t0_); H0 = fmaf(H0, sg8, t1_); L1 = fmaf(L1, sg8, t2_); H1 = fmaf(H1, sg8, t3_); \
    L2 = fmaf(L2, sg8, t4_); H2 = fmaf(H2, sg8, t5_); L3 = fmaf(L3, sg8, t6_); H3 = fmaf(H3, sg8, t7_); } \
  { swap16f(L0, H0); swap16f(L1, H1); swap16f(L2, H2); swap16f(L3, H3); \
    float aa_; \
    aa_ = L0 + H0; H0 = L0 - H0; L0 = aa_; \
    aa_ = L1 + H1; H1 = L1 - H1; L1 = aa_; \
    aa_ = L2 + H2; H2 = L2 - H2; L2 = aa_; \
    aa_ = L3 + H3; H3 = L3 - H3; L3 = aa_; \
    swap16f(L0, H0); swap16f(L1, H1); swap16f(L2, H2); swap16f(L3, H3); } \
  { swap32f(L0, H0); swap32f(L1, H1); swap32f(L2, H2); swap32f(L3, H3); \
    float aa_; \
    aa_ = L0 + H0; H0 = L0 - H0; L0 = aa_; \
    aa_ = L1 + H1; H1 = L1 - H1; L1 = aa_; \
    aa_ = L2 + H2; H2 = L2 - H2; L2 = aa_; \
    aa_ = L3 + H3; H3 = L3 - H3; L3 = aa_; \
    swap32f(L0, H0); swap32f(L1, H1); swap32f(L2, H2); swap32f(L3, H3); } }

__global__ __launch_bounds__(256) void k2_features(const float* __restrict__ sub,
                                                   const int* __restrict__ list,
                                                   const int* __restrict__ meta,
                                                   const int* __restrict__ Z,
                                                   const float* __restrict__ Dmat,
                                                   const float* __restrict__ bias,
                                                   const float* __restrict__ alpha,
                                                   float* __restrict__ out) {
  const int total = meta[8];
  const int w = threadIdx.x >> 6, lane = threadIdx.x & 63;
  const int pos0 = blockIdx.x * 4;             // block covers 4 positions, all 32 stacks
  if (pos0 >= total) return;
  const int sbeg = w * 8, send = sbeg + 8;     // this wave's 8 stacks
  const bool has1 = (pos0 + 1) < total;
  const bool has2 = (pos0 + 2) < total;
  const bool has3 = (pos0 + 3) < total;

  const float sg1 = (lane & 1) ? -1.0f : 1.0f;
  const float sg2 = (lane & 2) ? -1.0f : 1.0f;
  const float sg4 = (lane & 4) ? -1.0f : 1.0f;
  const float sg8 = (lane & 8) ? -1.0f : 1.0f;

  const int aid0 = list[pos0];
  const int e0 = elem_of(Z[aid0]);
  const float slo0 = sub[(size_t)pos0 * 128 + lane];
  const float shi0 = sub[(size_t)pos0 * 128 + 64 + lane];

  int aid1 = aid0, e1 = e0; float slo1 = 0.0f, shi1 = 0.0f;
  if (has1) {
    aid1 = list[pos0 + 1]; e1 = elem_of(Z[aid1]);
    slo1 = sub[(size_t)(pos0 + 1) * 128 + lane];
    shi1 = sub[(size_t)(pos0 + 1) * 128 + 64 + lane];
  }
  int aid2 = aid0, e2 = e0; float slo2 = 0.0f, shi2 = 0.0f;
  if (has2) {
    aid2 = list[pos0 + 2]; e2 = elem_of(Z[aid2]);
    slo2 = sub[(size_t)(pos0 + 2) * 128 + lane];
    shi2 = sub[(size_t)(pos0 + 2) * 128 + 64 + lane];
  }
  int aid3 = aid0, e3 = e0; float slo3 = 0.0f, shi3 = 0.0f;
  if (has3) {
    aid3 = list[pos0 + 3]; e3 = elem_of(Z[aid3]);
    slo3 = sub[(size_t)(pos0 + 3) * 128 + lane];
    shi3 = sub[(size_t)(pos0 + 3) * 128 + 64 + lane];
  }

  const float* De0 = Dmat + e0 * (2 * NSTACKS * NPCAS);
  const float* be0 = bias + e0 * NFEAT;

  float acc0 = 0.0f, acc1 = 0.0f, acc2 = 0.0f, acc3 = 0.0f;

  if (e0 == e1 && e1 == e2 && e2 == e3) {
    // -------- fast path: one coefficient set feeds all 4 chains --------
    for (int s = sbeg; s < send; ++s) {
      const int s0 = s * 128, s1 = (NSTACKS + s) * 128;
      const float d0lo = De0[s0 + lane], d0hi = De0[s0 + 64 + lane];
      const float d1lo = De0[s1 + lane], d1hi = De0[s1 + 64 + lane];
      const float blo  = be0[s0 + lane], bhi  = be0[s0 + 64 + lane];
      const float alo  = alpha[s0 + lane], ahi = alpha[s0 + 64 + lane];

      float lo0 = slo0 * d0lo, hi0 = shi0 * d0hi;
      float lo1 = slo1 * d0lo, hi1 = shi1 * d0hi;
      float lo2 = slo2 * d0lo, hi2 = shi2 * d0hi;
      float lo3 = slo3 * d0lo, hi3 = shi3 * d0hi;

      FW128X4(lo0, hi0, lo1, hi1, lo2, hi2, lo3, hi3)

      lo0 *= d1lo; hi0 *= d1hi;
      lo1 *= d1lo; hi1 *= d1hi;
      lo2 *= d1lo; hi2 *= d1hi;
      lo3 *= d1lo; hi3 *= d1hi;

      FW128X4(lo0, hi0, lo1, hi1, lo2, hi2, lo3, hi3)

      acc0 = fmaf(__cosf(fmaf(lo0, SCALE_C, blo)), alo, acc0);
      acc0 = fmaf(__cosf(fmaf(hi0, SCALE_C, bhi)), ahi, acc0);
      acc1 = fmaf(__cosf(fmaf(lo1, SCALE_C, blo)), alo, acc1);
      acc1 = fmaf(__cosf(fmaf(hi1, SCALE_C, bhi)), ahi, acc1);
      acc2 = fmaf(__cosf(fmaf(lo2, SCALE_C, blo)), alo, acc2);
      acc2 = fmaf(__cosf(fmaf(hi2, SCALE_C, bhi)), ahi, acc2);
      acc3 = fmaf(__cosf(fmaf(lo3, SCALE_C, blo)), alo, acc3);
      acc3 = fmaf(__cosf(fmaf(hi3, SCALE_C, bhi)), ahi, acc3);
    }
  } else {
    // -------- mixed-element fallback: per-chain loads --------
    const float* De1 = Dmat + e1 * (2 * NSTACKS * NPCAS);
    const float* De2 = Dmat + e2 * (2 * NSTACKS * NPCAS);
    const float* De3 = Dmat + e3 * (2 * NSTACKS * NPCAS);
    const float* be1 = bias + e1 * NFEAT;
    const float* be2 = bias + e2 * NFEAT;
    const float* be3 = bias + e3 * NFEAT;

    for (int s = sbeg; s < send; ++s) {
      const int s0 = s * 128, s1 = (NSTACKS + s) * 128;
      const float alo = alpha[s0 + lane], ahi = alpha[s0 + 64 + lane];

      float lo0 = slo0 * De0[s0 + lane], hi0 = shi0 * De0[s0 + 64 + lane];
      float lo1 = slo1 * De1[s0 + lane], hi1 = shi1 * De1[s0 + 64 + lane];
      float lo2 = slo2 * De2[s0 + lane], hi2 = shi2 * De2[s0 + 64 + lane];
      float lo3 = slo3 * De3[s0 + lane], hi3 = shi3 * De3[s0 + 64 + lane];

      FW128X4(lo0, hi0, lo1, hi1, lo2, hi2, lo3, hi3)

      lo0 *= De0[s1 + lane]; hi0 *= De0[s1 + 64 + lane];
      lo1 *= De1[s1 + lane]; hi1 *= De1[s1 + 64 + lane];
      lo2 *= De2[s1 + lane]; hi2 *= De2[s1 + 64 + lane];
      lo3 *= De3[s1 + lane]; hi3 *= De3[s1 + 64 + lane];

      FW128X4(lo0, hi0, lo1, hi1, lo2, hi2, lo3, hi3)

      acc0 = fmaf(__cosf(fmaf(lo0, SCALE_C, be0[s0 + lane])),      alo, acc0);
      acc0 = fmaf(__cosf(fmaf(hi0, SCALE_C, be0[s0 + 64 + lane])), ahi, acc0);
      acc1 = fmaf(__cosf(fmaf(lo1, SCALE_C, be1[s0 + lane])),      alo, acc1);
      acc1 = fmaf(__cosf(fmaf(hi1, SCALE_C, be1[s0 + 64 + lane])), ahi, acc1);
      acc2 = fmaf(__cosf(fmaf(lo2, SCALE_C, be2[s0 + lane])),      alo, acc2);
      acc2 = fmaf(__cosf(fmaf(hi2, SCALE_C, be2[s0 + 64 + lane])), ahi, acc2);
      acc3 = fmaf(__cosf(fmaf(lo3, SCALE_C, be3[s0 + lane])),      alo, acc3);
      acc3 = fmaf(__cosf(fmaf(hi3, SCALE_C, be3[s0 + 64 + lane])), ahi, acc3);
    }
  }

  #pragma unroll
  for (int o = 32; o > 0; o >>= 1) {
    acc0 += __shfl_xor(acc0, o, 64);
    acc1 += __shfl_xor(acc1, o, 64);
    acc2 += __shfl_xor(acc2, o, 64);
    acc3 += __shfl_xor(acc3, o, 64);
  }
  if (lane == 0)         atomicAdd(out + (aid0 >> 5), acc0 * FEATN_C);
  if (lane == 1 && has1) atomicAdd(out + (aid1 >> 5), acc1 * FEATN_C);
  if (lane == 2 && has2) atomicAdd(out + (aid2 >> 5), acc2 * FEATN_C);
  if (lane == 3 && has3) atomicAdd(out + (aid3 >> 5), acc3 * FEATN_C);
}

extern "C" void kernel_launch(void* const* d_in, const int* in_sizes, int n_in,
                              void* d_out, int out_size, void* d_ws, size_t ws_size,
                              hipStream_t stream) {
  const float* rep       = (const float*)d_in[0];
  const int*   Z         = (const int*)  d_in[1];
  const float* reductors = (const float*)d_in[2];
  const float* Dmat      = (const float*)d_in[3];
  const float* bias      = (const float*)d_in[4];
  const float* alpha     = (const float*)d_in[5];
  float* out = (float*)d_out;

  char* wsb = (char*)d_ws;
  int*   list = (int*)(wsb + LIST_OFF);
  int*   meta = (int*)(wsb + META_OFF);
  float* sub  = (float*)(wsb + SUB_OFF);

  k0_bucket<<<1, 256, 0, stream>>>(Z, list, meta, out);
  dim3 g1(32, 4);                        // 64-atom tiles (verified R3 config)
  k1_matvec<<<g1, 256, 0, stream>>>(rep, reductors, list, meta, sub);
  k2_features<<<2048, 256, 0, stream>>>(sub, list, meta, Z, Dmat, bias, alpha, out);
}